// Round 6
// baseline (956.934 us; speedup 1.0000x reference)
//
#include <hip/hip_runtime.h>
#include <hip/hip_bf16.h>

#define N_NODES   50000
#define N_EDGES   800000
#define IN_DIM    128
#define EDGE_DIM  32
#define HIDDEN    128
#define NUM_LAYERS 3
#define BN_EPS    1e-5f
#define RES_SCALE 0.1f

typedef unsigned int   u32;
typedef unsigned short u16;
typedef _Float16 half2_t __attribute__((ext_vector_type(2)));
typedef unsigned int u32x4 __attribute__((ext_vector_type(4)));
typedef float f32x4 __attribute__((ext_vector_type(4)));

#define AS4 __attribute__((address_space(4)))

__device__ __forceinline__ half2_t as_half2(u32 v) {
    union { u32 u; half2_t h; } c; c.u = v; return c.h;
}
__device__ __forceinline__ u32 pack_half2(float a, float b) {
    union { u32 u; half2_t h; } c;
    c.h.x = (_Float16)a; c.h.y = (_Float16)b; return c.u;
}

#if defined(__has_builtin)
#if __has_builtin(__builtin_amdgcn_fdot2)
#define HAVE_FDOT2 1
#endif
#endif

__device__ __forceinline__ float fdot2f(half2_t a, half2_t b, float c) {
#ifdef HAVE_FDOT2
    return __builtin_amdgcn_fdot2(a, b, c, false);
#else
    c = fmaf((float)a.x, (float)b.x, c);
    c = fmaf((float)a.y, (float)b.y, c);
    return c;
#endif
}

// ---------------- pack x -> h16 ; zero deg ; zero stats ----------------
__global__ __launch_bounds__(256) void init_kernel(const float* __restrict__ x,
                                                   u32* __restrict__ h16,
                                                   u32* __restrict__ deg,
                                                   float* __restrict__ statsAll) {
    int idx = blockIdx.x * 256 + threadIdx.x;
    if (idx < N_NODES * 64) {
        int n = idx >> 6, l = idx & 63;
        float a = x[n * HIDDEN + l];
        float b = x[n * HIDDEN + 64 + l];
        h16[idx] = pack_half2(a, b);
    }
    if (idx < N_NODES) deg[idx] = 0u;
    if (idx < NUM_LAYERS * 256) statsAll[idx] = 0.f;
}

// ---------------- degree histogram ----------------
__global__ __launch_bounds__(256) void hist_kernel(const int* __restrict__ ei,
                                                   u32* __restrict__ deg) {
    int e = blockIdx.x * 256 + threadIdx.x;
    if (e < N_EDGES) atomicAdd(&deg[ei[N_EDGES + e]], 1u);
}

// ---------------- multi-block exclusive scan (3 passes) ----------------
#define SCAN_NB ((N_NODES + 255) / 256)   // 196

__global__ __launch_bounds__(256) void scan1_kernel(const u32* __restrict__ deg,
                                                    u32* __restrict__ bsum) {
    int i = blockIdx.x * 256 + threadIdx.x;
    u32 v = (i < N_NODES) ? deg[i] : 0u;
    v += __shfl_down(v, 32, 64);
    v += __shfl_down(v, 16, 64);
    v += __shfl_down(v, 8, 64);
    v += __shfl_down(v, 4, 64);
    v += __shfl_down(v, 2, 64);
    v += __shfl_down(v, 1, 64);
    __shared__ u32 ws[4];
    if ((threadIdx.x & 63) == 0) ws[threadIdx.x >> 6] = v;
    __syncthreads();
    if (threadIdx.x == 0) bsum[blockIdx.x] = ws[0] + ws[1] + ws[2] + ws[3];
}

__global__ __launch_bounds__(256) void scan2_kernel(const u32* __restrict__ bsum,
                                                    u32* __restrict__ bbase,
                                                    u32* __restrict__ off) {
    __shared__ u32 tmp[256];
    int t = threadIdx.x;
    u32 v = (t < SCAN_NB) ? bsum[t] : 0u;
    tmp[t] = v;
    __syncthreads();
    for (int d = 1; d < 256; d <<= 1) {
        u32 u = (t >= d) ? tmp[t - d] : 0u;
        __syncthreads();
        tmp[t] += u;
        __syncthreads();
    }
    if (t < SCAN_NB) bbase[t] = (t == 0) ? 0u : tmp[t - 1];
    if (t == 255) off[N_NODES] = tmp[255];   // grand total
}

__global__ __launch_bounds__(256) void scan3_kernel(const u32* __restrict__ deg,
                                                    const u32* __restrict__ bbase,
                                                    u32* __restrict__ off,
                                                    u32* __restrict__ cursor) {
    __shared__ u32 tmp[256];
    int t = threadIdx.x;
    int i = blockIdx.x * 256 + t;
    u32 v = (i < N_NODES) ? deg[i] : 0u;
    tmp[t] = v;
    __syncthreads();
    for (int d = 1; d < 256; d <<= 1) {
        u32 u = (t >= d) ? tmp[t - d] : 0u;
        __syncthreads();
        tmp[t] += u;
        __syncthreads();
    }
    if (i < N_NODES) {
        u32 excl = bbase[blockIdx.x] + tmp[t] - v;
        off[i] = excl;
        cursor[i] = excl;
    }
}

// ---------------- scatter edges into CSR order + permute ea (f16) ----------------
__global__ __launch_bounds__(256) void scatter_kernel(const int* __restrict__ ei,
                                                      u32* __restrict__ cursor,
                                                      int* __restrict__ ssrc,
                                                      const float* __restrict__ ea,
                                                      _Float16* __restrict__ ea_perm) {
    int e = blockIdx.x * 256 + threadIdx.x;
    if (e >= N_EDGES) return;
    int dst = ei[N_EDGES + e];
    u32 pos = atomicAdd(&cursor[dst], 1u);
    ssrc[pos] = ei[e];
    const float4* src = (const float4*)(ea + (size_t)e * EDGE_DIM);
    u32 buf[16];
#pragma unroll
    for (int q = 0; q < 8; q++) {
        float4 v = src[q];
        buf[2 * q + 0] = pack_half2(v.x, v.y);
        buf[2 * q + 1] = pack_half2(v.z, v.w);
    }
    uint4* dp = (uint4*)(ea_perm + (size_t)pos * EDGE_DIM);
#pragma unroll
    for (int q = 0; q < 4; q++)
        dp[q] = make_uint4(buf[4 * q], buf[4 * q + 1], buf[4 * q + 2], buf[4 * q + 3]);
}

// dot of one ea row (4 x u32x4 in SGPRs = 32 halves) against wlo/whi
__device__ __forceinline__ void edot4(const u32x4* __restrict__ d,
                                      const half2_t* __restrict__ wlo,
                                      const half2_t* __restrict__ whi,
                                      float& dl, float& dh) {
#pragma unroll
    for (int q = 0; q < 4; q++) {
        u32x4 v = d[q];
        dl = fdot2f(as_half2(v.x), wlo[q * 4 + 0], dl);
        dh = fdot2f(as_half2(v.x), whi[q * 4 + 0], dh);
        dl = fdot2f(as_half2(v.y), wlo[q * 4 + 1], dl);
        dh = fdot2f(as_half2(v.y), whi[q * 4 + 1], dh);
        dl = fdot2f(as_half2(v.z), wlo[q * 4 + 2], dl);
        dh = fdot2f(as_half2(v.z), whi[q * 4 + 2], dh);
        dl = fdot2f(as_half2(v.w), wlo[q * 4 + 3], dl);
        dh = fdot2f(as_half2(v.w), whi[q * 4 + 3], dh);
    }
}

// ---------------- CSR aggregation: one WAVE per node slot ----------------
__global__ __launch_bounds__(256) void agg_perm_kernel(
    const u32* __restrict__ h16, const _Float16* __restrict__ ea_perm,
    const int* __restrict__ ssrc, const u32* __restrict__ off,
    const float* __restrict__ We, const float* __restrict__ be,
    float* __restrict__ z) {
    int t = threadIdx.x;
    int lane = t & 63;
    half2_t wlo[16], whi[16];
#pragma unroll
    for (int k = 0; k < 16; k++) {
        half2_t a, b;
        a.x = (_Float16)We[(2 * k + 0) * HIDDEN + lane];
        a.y = (_Float16)We[(2 * k + 1) * HIDDEN + lane];
        b.x = (_Float16)We[(2 * k + 0) * HIDDEN + 64 + lane];
        b.y = (_Float16)We[(2 * k + 1) * HIDDEN + 64 + lane];
        wlo[k] = a; whi[k] = b;
    }
    float blo = be[lane], bhi = be[64 + lane];

    const AS4 int*   cssrc = (const AS4 int*)(unsigned long long)ssrc;
    const AS4 u32*   coff  = (const AS4 u32*)(unsigned long long)off;
    const AS4 u32x4* cea   = (const AS4 u32x4*)(unsigned long long)ea_perm; // 4 x u32x4 per edge

    int wid = __builtin_amdgcn_readfirstlane(t >> 6);
    int slot = blockIdx.x * 4 + wid;
    int nslots = gridDim.x * 4;
    for (int n = slot; n < N_NODES; n += nslots) {
        int e0 = (int)coff[n], e1 = (int)coff[n + 1];
        float al0 = 0.f, ah0 = 0.f, al1 = 0.f, ah1 = 0.f;
        int e = e0;
        if (e + 2 <= e1) {
            int s0 = cssrc[e], s1 = cssrc[e + 1];
            u32x4 A0[4], A1[4];
#pragma unroll
            for (int q = 0; q < 4; q++) { A0[q] = cea[e * 4 + q]; A1[q] = cea[e * 4 + 4 + q]; }
            while (true) {
                u32 g0 = h16[s0 * 64 + lane];
                u32 g1 = h16[s1 * 64 + lane];
                int en = e + 2;
                int more = (en + 2 <= e1);
                float d0l = 0.f, d0h = 0.f, d1l = 0.f, d1h = 0.f;
                edot4(A0, wlo, whi, d0l, d0h);
                edot4(A1, wlo, whi, d1l, d1h);
                int ns0 = s0, ns1 = s1;
                if (more) {
                    ns0 = cssrc[en]; ns1 = cssrc[en + 1];
#pragma unroll
                    for (int q = 0; q < 4; q++) { A0[q] = cea[en * 4 + q]; A1[q] = cea[en * 4 + 4 + q]; }
                }
                half2_t hh0 = as_half2(g0), hh1 = as_half2(g1);
                al0 += fmaxf(d0l + blo + (float)hh0.x, 0.f);
                ah0 += fmaxf(d0h + bhi + (float)hh0.y, 0.f);
                al1 += fmaxf(d1l + blo + (float)hh1.x, 0.f);
                ah1 += fmaxf(d1h + bhi + (float)hh1.y, 0.f);
                e = en;
                if (!more) break;
                s0 = ns0; s1 = ns1;
            }
        }
        if (e < e1) {  // tail: one edge
            int s0 = cssrc[e];
            u32x4 A0[4];
#pragma unroll
            for (int q = 0; q < 4; q++) A0[q] = cea[e * 4 + q];
            float dl = 0.f, dh = 0.f;
            edot4(A0, wlo, whi, dl, dh);
            half2_t hh = as_half2(h16[s0 * 64 + lane]);
            al0 += fmaxf(dl + blo + (float)hh.x, 0.f);
            ah0 += fmaxf(dh + bhi + (float)hh.y, 0.f);
        }
        half2_t self = as_half2(h16[n * 64 + lane]);
        z[n * HIDDEN + lane]      = (float)self.x + al0 + al1;
        z[n * HIDDEN + 64 + lane] = (float)self.y + ah0 + ah1;
    }
}

// ---------------- fused MLP v3: 128 nodes/block, W via SGPR, XOR-swizzled LDS ----------------
// Wave w owns features [32w,32w+32); lane l owns nodes (l, 64+l). Per k-step:
// 8 wave-uniform s_load_dwordx4 of W feed 64 FMAs (128 cyc/wave) -> with
// unroll-2 the prefetch distance covers K$-miss latency even at 2 waves/SIMD.
// zT[k*128 + (n^k)] swizzle: conflict-free compute reads and h1 writes.
__device__ __forceinline__ void gemm_sgpr(const AS4 f32x4* __restrict__ cW,
                                          const AS4 f32x4* __restrict__ cB,
                                          const float* __restrict__ zT,
                                          int l, int fb,
                                          float* __restrict__ acc0,
                                          float* __restrict__ acc1) {
#pragma unroll
    for (int q = 0; q < 8; q++) {
        f32x4 bb = cB[fb + q];
        acc0[4*q+0] = bb.x; acc0[4*q+1] = bb.y; acc0[4*q+2] = bb.z; acc0[4*q+3] = bb.w;
        acc1[4*q+0] = bb.x; acc1[4*q+1] = bb.y; acc1[4*q+2] = bb.z; acc1[4*q+3] = bb.w;
    }
    f32x4 wreg[8];
#pragma unroll
    for (int q = 0; q < 8; q++) wreg[q] = cW[fb + q];
#pragma unroll 2
    for (int k = 0; k < 128; k++) {
        int kn = (k + 1) & 127;
        f32x4 wn[8];
#pragma unroll
        for (int q = 0; q < 8; q++) wn[q] = cW[kn * 32 + fb + q];
        int s0 = k * 128 + (l ^ k);
        float zv0 = zT[s0];
        float zv1 = zT[s0 ^ 64];
#pragma unroll
        for (int q = 0; q < 8; q++) {
#pragma unroll
            for (int i = 0; i < 4; i++) {
                acc0[4*q+i] = fmaf(zv0, wreg[q][i], acc0[4*q+i]);
                acc1[4*q+i] = fmaf(zv1, wreg[q][i], acc1[4*q+i]);
            }
        }
#pragma unroll
        for (int q = 0; q < 8; q++) wreg[q] = wn[q];
    }
}

__global__ __launch_bounds__(256) void fused_mlp_kernel(
    const float* __restrict__ zin,
    const float* __restrict__ W1_, const float* __restrict__ b1_,
    const float* __restrict__ W2_, const float* __restrict__ b2_,
    float* __restrict__ z2, float* __restrict__ stats) {
    __shared__ float zT[128 * 128];      // 64 KB, swizzled [k][n^k]
    int t = threadIdx.x;
    int l = t & 63;
    int w = t >> 6;
    int fb = __builtin_amdgcn_readfirstlane(w * 8);   // f32x4 units: feats [32w,32w+32)
    int base = blockIdx.x * 128;

    const AS4 f32x4* cW1 = (const AS4 f32x4*)(unsigned long long)W1_;
    const AS4 f32x4* cW2 = (const AS4 f32x4*)(unsigned long long)W2_;
    const AS4 f32x4* cB1 = (const AS4 f32x4*)(unsigned long long)b1_;
    const AS4 f32x4* cB2 = (const AS4 f32x4*)(unsigned long long)b2_;

    // stage z tile (coalesced float4 reads, swizzled LDS writes)
    {
        int n0 = t >> 5, k4 = (t & 31) * 4;
        for (int rep = 0; rep < 16; rep++) {
            int nn = n0 + rep * 8;
            int gn = base + nn;
            float4 v = make_float4(0.f, 0.f, 0.f, 0.f);
            if (gn < N_NODES) v = *(const float4*)(zin + (size_t)gn * HIDDEN + k4);
            zT[(k4 + 0) * 128 + (nn ^ (k4 + 0))] = v.x;
            zT[(k4 + 1) * 128 + (nn ^ (k4 + 1))] = v.y;
            zT[(k4 + 2) * 128 + (nn ^ (k4 + 2))] = v.z;
            zT[(k4 + 3) * 128 + (nn ^ (k4 + 3))] = v.w;
        }
    }
    __syncthreads();

    float acc0[32], acc1[32];
    // GEMM1: h1 = relu(z @ W1 + b1)
    gemm_sgpr(cW1, cB1, zT, l, fb, acc0, acc1);
    __syncthreads();
#pragma unroll
    for (int j = 0; j < 32; j++) {
        int kf = w * 32 + j;
        int s = kf * 128 + (l ^ kf);
        zT[s]      = fmaxf(acc0[j], 0.f);
        zT[s ^ 64] = fmaxf(acc1[j], 0.f);
    }
    __syncthreads();
    // GEMM2: z2 = h1 @ W2 + b2
    gemm_sgpr(cW2, cB2, zT, l, fb, acc0, acc1);
    __syncthreads();
    {
        bool ok0 = (base + l) < N_NODES;
        bool ok1 = (base + 64 + l) < N_NODES;
#pragma unroll
        for (int j = 0; j < 32; j++) {
            int kf = w * 32 + j;
            int s = kf * 128 + (l ^ kf);
            zT[s]      = ok0 ? acc0[j] : 0.f;
            zT[s ^ 64] = ok1 ? acc1[j] : 0.f;
        }
    }
    __syncthreads();
    // coalesced store
    {
        int n0 = t >> 5, k4 = (t & 31) * 4;
        for (int rep = 0; rep < 16; rep++) {
            int nn = n0 + rep * 8;
            int gn = base + nn;
            if (gn < N_NODES) {
                float4 v;
                v.x = zT[(k4 + 0) * 128 + (nn ^ (k4 + 0))];
                v.y = zT[(k4 + 1) * 128 + (nn ^ (k4 + 1))];
                v.z = zT[(k4 + 2) * 128 + (nn ^ (k4 + 2))];
                v.w = zT[(k4 + 3) * 128 + (nn ^ (k4 + 3))];
                *(float4*)(z2 + (size_t)gn * HIDDEN + k4) = v;
            }
        }
    }
    // fused BN stats: per-feature sum/sumsq over this block's nodes (OOB = 0)
    {
        int f = t & 127, half = t >> 7;
        int rowb = f * 128;
        float s = 0.f, sq = 0.f;
#pragma unroll 8
        for (int n = half * 64; n < half * 64 + 64; n++) {
            float v = zT[rowb + (n ^ f)];
            s += v; sq = fmaf(v, v, sq);
        }
        unsafeAtomicAdd(&stats[f], s);
        unsafeAtomicAdd(&stats[128 + f], sq);
    }
}

// ---------------- batchnorm + relu + residual (paired features) ----------------
__global__ __launch_bounds__(256) void bn_kernel(
    const float* __restrict__ z2, const float* __restrict__ stats,
    const float* __restrict__ gamma, const float* __restrict__ beta,
    u32* __restrict__ h16, float* __restrict__ out, int write_out) {
    int idx = blockIdx.x * 256 + threadIdx.x;
    if (idx >= N_NODES * 64) return;
    int n = idx >> 6, l = idx & 63;
    const float inv_n = 1.0f / (float)N_NODES;
    float mu_l = stats[l] * inv_n;
    float mu_h = stats[64 + l] * inv_n;
    float var_l = stats[HIDDEN + l] * inv_n - mu_l * mu_l;
    float var_h = stats[HIDDEN + 64 + l] * inv_n - mu_h * mu_h;
    float inv_l = rsqrtf(var_l + BN_EPS);
    float inv_h = rsqrtf(var_h + BN_EPS);
    float zl = (z2[n * HIDDEN + l]      - mu_l) * inv_l * gamma[l]      + beta[l];
    float zh = (z2[n * HIDDEN + 64 + l] - mu_h) * inv_h * gamma[64 + l] + beta[64 + l];
    zl = fmaxf(zl, 0.f);
    zh = fmaxf(zh, 0.f);
    half2_t hh = as_half2(h16[idx]);
    float hn_l = fmaf(RES_SCALE, (float)hh.x, zl);
    float hn_h = fmaf(RES_SCALE, (float)hh.y, zh);
    h16[idx] = pack_half2(hn_l, hn_h);
    if (write_out) {
        out[n * HIDDEN + l] = hn_l;
        out[n * HIDDEN + 64 + l] = hn_h;
    }
}

extern "C" void kernel_launch(void* const* d_in, const int* in_sizes, int n_in,
                              void* d_out, int out_size, void* d_ws, size_t ws_size,
                              hipStream_t stream) {
    const float* x     = (const float*)d_in[0];
    const int*   ei    = (const int*)d_in[1];
    const float* ea    = (const float*)d_in[2];
    const float* We    = (const float*)d_in[3];
    const float* be    = (const float*)d_in[4];
    const float* W1    = (const float*)d_in[5];
    const float* b1    = (const float*)d_in[6];
    const float* W2    = (const float*)d_in[7];
    const float* b2    = (const float*)d_in[8];
    const float* gamma = (const float*)d_in[9];
    const float* beta  = (const float*)d_in[10];
    float* out = (float*)d_out;

    char* wsp = (char*)d_ws;
    const size_t NH = (size_t)N_NODES * HIDDEN;
    u32*      h16    = (u32*)wsp;      wsp += (size_t)N_NODES * 64 * 4;        // 12.8 MB
    float*    z      = (float*)wsp;    wsp += NH * 4;                          // 25.6 MB
    _Float16* ea_perm= (_Float16*)wsp; wsp += (size_t)N_EDGES * EDGE_DIM * 2;  // 51.2 MB
    float*    statsA = (float*)wsp;    wsp += (size_t)NUM_LAYERS * 256 * 4;
    u32*      deg    = (u32*)wsp;      wsp += (size_t)N_NODES * 4;
    u32*      cursor = (u32*)wsp;      wsp += (size_t)N_NODES * 4;
    int*      ssrc   = (int*)wsp;      wsp += (size_t)N_EDGES * 4;
    u32*      off    = (u32*)wsp;      wsp += (size_t)(N_NODES + 1) * 4;
    u32*      bsum   = (u32*)wsp;      wsp += (size_t)SCAN_NB * 4;
    u32*      bbase  = (u32*)wsp;      wsp += (size_t)SCAN_NB * 4;

    const int p_blocks  = (N_NODES * 64 + 255) / 256;       // 12500
    const int e_blocks  = (N_EDGES + 255) / 256;            // 3125
    const int m_blocks  = (N_NODES + 127) / 128;            // 391

    // CSR build (once per call)
    init_kernel<<<p_blocks, 256, 0, stream>>>(x, h16, deg, statsA);
    hist_kernel<<<e_blocks, 256, 0, stream>>>(ei, deg);
    scan1_kernel<<<SCAN_NB, 256, 0, stream>>>(deg, bsum);
    scan2_kernel<<<1, 256, 0, stream>>>(bsum, bbase, off);
    scan3_kernel<<<SCAN_NB, 256, 0, stream>>>(deg, bbase, off, cursor);
    scatter_kernel<<<e_blocks, 256, 0, stream>>>(ei, cursor, ssrc, ea, ea_perm);

    for (int l = 0; l < NUM_LAYERS; l++) {
        agg_perm_kernel<<<4096, 256, 0, stream>>>(
            h16, ea_perm, ssrc, off,
            We + (size_t)l * EDGE_DIM * HIDDEN, be + (size_t)l * HIDDEN, z);
        fused_mlp_kernel<<<m_blocks, 256, 0, stream>>>(
            z, W1 + (size_t)l * HIDDEN * HIDDEN, b1 + (size_t)l * HIDDEN,
            W2 + (size_t)l * HIDDEN * HIDDEN, b2 + (size_t)l * HIDDEN,
            z, statsA + (size_t)l * 256);
        bn_kernel<<<p_blocks, 256, 0, stream>>>(
            z, statsA + (size_t)l * 256, gamma + (size_t)l * HIDDEN, beta + (size_t)l * HIDDEN,
            h16, out, (l == NUM_LAYERS - 1) ? 1 : 0);
    }
}

// Round 7
// 623.363 us; speedup vs baseline: 1.5351x; 1.5351x over previous
//
#include <hip/hip_runtime.h>
#include <hip/hip_bf16.h>

#define N_NODES   50000
#define N_EDGES   800000
#define IN_DIM    128
#define EDGE_DIM  32
#define HIDDEN    128
#define NUM_LAYERS 3
#define BN_EPS    1e-5f
#define RES_SCALE 0.1f

typedef unsigned int   u32;
typedef unsigned short u16;
typedef _Float16 half2_t __attribute__((ext_vector_type(2)));
typedef _Float16 half8 __attribute__((ext_vector_type(8)));
typedef unsigned int u32x4 __attribute__((ext_vector_type(4)));
typedef float f32x4 __attribute__((ext_vector_type(4)));

#define AS4 __attribute__((address_space(4)))

__device__ __forceinline__ half2_t as_half2(u32 v) {
    union { u32 u; half2_t h; } c; c.u = v; return c.h;
}
__device__ __forceinline__ u32 pack_half2(float a, float b) {
    union { u32 u; half2_t h; } c;
    c.h.x = (_Float16)a; c.h.y = (_Float16)b; return c.u;
}

#if defined(__has_builtin)
#if __has_builtin(__builtin_amdgcn_fdot2)
#define HAVE_FDOT2 1
#endif
#endif

__device__ __forceinline__ float fdot2f(half2_t a, half2_t b, float c) {
#ifdef HAVE_FDOT2
    return __builtin_amdgcn_fdot2(a, b, c, false);
#else
    c = fmaf((float)a.x, (float)b.x, c);
    c = fmaf((float)a.y, (float)b.y, c);
    return c;
#endif
}

// ---------------- pack x -> h16 ; zero deg ; zero stats ----------------
__global__ __launch_bounds__(256) void init_kernel(const float* __restrict__ x,
                                                   u32* __restrict__ h16,
                                                   u32* __restrict__ deg,
                                                   float* __restrict__ statsAll) {
    int idx = blockIdx.x * 256 + threadIdx.x;
    if (idx < N_NODES * 64) {
        int n = idx >> 6, l = idx & 63;
        float a = x[n * HIDDEN + l];
        float b = x[n * HIDDEN + 64 + l];
        h16[idx] = pack_half2(a, b);
    }
    if (idx < N_NODES) deg[idx] = 0u;
    if (idx < NUM_LAYERS * 256) statsAll[idx] = 0.f;
}

// ---------------- degree histogram ----------------
__global__ __launch_bounds__(256) void hist_kernel(const int* __restrict__ ei,
                                                   u32* __restrict__ deg) {
    int e = blockIdx.x * 256 + threadIdx.x;
    if (e < N_EDGES) atomicAdd(&deg[ei[N_EDGES + e]], 1u);
}

// ---------------- multi-block exclusive scan (3 passes) ----------------
#define SCAN_NB ((N_NODES + 255) / 256)   // 196

__global__ __launch_bounds__(256) void scan1_kernel(const u32* __restrict__ deg,
                                                    u32* __restrict__ bsum) {
    int i = blockIdx.x * 256 + threadIdx.x;
    u32 v = (i < N_NODES) ? deg[i] : 0u;
    v += __shfl_down(v, 32, 64);
    v += __shfl_down(v, 16, 64);
    v += __shfl_down(v, 8, 64);
    v += __shfl_down(v, 4, 64);
    v += __shfl_down(v, 2, 64);
    v += __shfl_down(v, 1, 64);
    __shared__ u32 ws[4];
    if ((threadIdx.x & 63) == 0) ws[threadIdx.x >> 6] = v;
    __syncthreads();
    if (threadIdx.x == 0) bsum[blockIdx.x] = ws[0] + ws[1] + ws[2] + ws[3];
}

__global__ __launch_bounds__(256) void scan2_kernel(const u32* __restrict__ bsum,
                                                    u32* __restrict__ bbase,
                                                    u32* __restrict__ off) {
    __shared__ u32 tmp[256];
    int t = threadIdx.x;
    u32 v = (t < SCAN_NB) ? bsum[t] : 0u;
    tmp[t] = v;
    __syncthreads();
    for (int d = 1; d < 256; d <<= 1) {
        u32 u = (t >= d) ? tmp[t - d] : 0u;
        __syncthreads();
        tmp[t] += u;
        __syncthreads();
    }
    if (t < SCAN_NB) bbase[t] = (t == 0) ? 0u : tmp[t - 1];
    if (t == 255) off[N_NODES] = tmp[255];   // grand total
}

__global__ __launch_bounds__(256) void scan3_kernel(const u32* __restrict__ deg,
                                                    const u32* __restrict__ bbase,
                                                    u32* __restrict__ off,
                                                    u32* __restrict__ cursor) {
    __shared__ u32 tmp[256];
    int t = threadIdx.x;
    int i = blockIdx.x * 256 + t;
    u32 v = (i < N_NODES) ? deg[i] : 0u;
    tmp[t] = v;
    __syncthreads();
    for (int d = 1; d < 256; d <<= 1) {
        u32 u = (t >= d) ? tmp[t - d] : 0u;
        __syncthreads();
        tmp[t] += u;
        __syncthreads();
    }
    if (i < N_NODES) {
        u32 excl = bbase[blockIdx.x] + tmp[t] - v;
        off[i] = excl;
        cursor[i] = excl;
    }
}

// ---------------- scatter edges into CSR order + permute ea (f16) ----------------
__global__ __launch_bounds__(256) void scatter_kernel(const int* __restrict__ ei,
                                                      u32* __restrict__ cursor,
                                                      int* __restrict__ ssrc,
                                                      const float* __restrict__ ea,
                                                      _Float16* __restrict__ ea_perm) {
    int e = blockIdx.x * 256 + threadIdx.x;
    if (e >= N_EDGES) return;
    int dst = ei[N_EDGES + e];
    u32 pos = atomicAdd(&cursor[dst], 1u);
    ssrc[pos] = ei[e];
    const float4* src = (const float4*)(ea + (size_t)e * EDGE_DIM);
    u32 buf[16];
#pragma unroll
    for (int q = 0; q < 8; q++) {
        float4 v = src[q];
        buf[2 * q + 0] = pack_half2(v.x, v.y);
        buf[2 * q + 1] = pack_half2(v.z, v.w);
    }
    uint4* dp = (uint4*)(ea_perm + (size_t)pos * EDGE_DIM);
#pragma unroll
    for (int q = 0; q < 4; q++)
        dp[q] = make_uint4(buf[4 * q], buf[4 * q + 1], buf[4 * q + 2], buf[4 * q + 3]);
}

// ---------------- W transpose+fp16 precompute ----------------
// w1t[l][f][k'] = (f16) W1[l][kmap(k')][f], kmap bakes the z16 pair-packing:
//   k' even -> k'=2i <-> feat i (lo half), k' odd -> 64 + (k'>>1) (hi half)
// w2t[l][f][k]  = (f16) W2[l][k][f]  (identity k)
__global__ __launch_bounds__(256) void wconv_kernel(const float* __restrict__ W1,
                                                    const float* __restrict__ W2,
                                                    _Float16* __restrict__ w1t,
                                                    _Float16* __restrict__ w2t) {
    int idx = blockIdx.x * 256 + threadIdx.x;
    if (idx >= NUM_LAYERS * 128 * 128) return;
    int kk = idx & 127, f = (idx >> 7) & 127, l = idx >> 14;
    int k1 = (kk & 1) ? 64 + (kk >> 1) : (kk >> 1);
    w1t[idx] = (_Float16)W1[l * 16384 + k1 * 128 + f];
    w2t[idx] = (_Float16)W2[l * 16384 + kk * 128 + f];
}

// dot of one ea row (4 x u32x4 in SGPRs = 32 halves) against wlo/whi
__device__ __forceinline__ void edot4(const u32x4* __restrict__ d,
                                      const half2_t* __restrict__ wlo,
                                      const half2_t* __restrict__ whi,
                                      float& dl, float& dh) {
#pragma unroll
    for (int q = 0; q < 4; q++) {
        u32x4 v = d[q];
        dl = fdot2f(as_half2(v.x), wlo[q * 4 + 0], dl);
        dh = fdot2f(as_half2(v.x), whi[q * 4 + 0], dh);
        dl = fdot2f(as_half2(v.y), wlo[q * 4 + 1], dl);
        dh = fdot2f(as_half2(v.y), whi[q * 4 + 1], dh);
        dl = fdot2f(as_half2(v.z), wlo[q * 4 + 2], dl);
        dh = fdot2f(as_half2(v.z), whi[q * 4 + 2], dh);
        dl = fdot2f(as_half2(v.w), wlo[q * 4 + 3], dl);
        dh = fdot2f(as_half2(v.w), whi[q * 4 + 3], dh);
    }
}

// ---------------- CSR aggregation: one WAVE per node slot ----------------
// Output: z16 packed fp16 pairs (feat l, feat 64+l) per lane -> one u32 store.
__global__ __launch_bounds__(256) void agg_perm_kernel(
    const u32* __restrict__ h16, const _Float16* __restrict__ ea_perm,
    const int* __restrict__ ssrc, const u32* __restrict__ off,
    const float* __restrict__ We, const float* __restrict__ be,
    u32* __restrict__ z16) {
    int t = threadIdx.x;
    int lane = t & 63;
    half2_t wlo[16], whi[16];
#pragma unroll
    for (int k = 0; k < 16; k++) {
        half2_t a, b;
        a.x = (_Float16)We[(2 * k + 0) * HIDDEN + lane];
        a.y = (_Float16)We[(2 * k + 1) * HIDDEN + lane];
        b.x = (_Float16)We[(2 * k + 0) * HIDDEN + 64 + lane];
        b.y = (_Float16)We[(2 * k + 1) * HIDDEN + 64 + lane];
        wlo[k] = a; whi[k] = b;
    }
    float blo = be[lane], bhi = be[64 + lane];

    const AS4 int*   cssrc = (const AS4 int*)(unsigned long long)ssrc;
    const AS4 u32*   coff  = (const AS4 u32*)(unsigned long long)off;
    const AS4 u32x4* cea   = (const AS4 u32x4*)(unsigned long long)ea_perm; // 4 x u32x4 per edge

    int wid = __builtin_amdgcn_readfirstlane(t >> 6);
    int slot = blockIdx.x * 4 + wid;
    int nslots = gridDim.x * 4;
    for (int n = slot; n < N_NODES; n += nslots) {
        int e0 = (int)coff[n], e1 = (int)coff[n + 1];
        float al0 = 0.f, ah0 = 0.f, al1 = 0.f, ah1 = 0.f;
        int e = e0;
        if (e + 2 <= e1) {
            int s0 = cssrc[e], s1 = cssrc[e + 1];
            u32x4 A0[4], A1[4];
#pragma unroll
            for (int q = 0; q < 4; q++) { A0[q] = cea[e * 4 + q]; A1[q] = cea[e * 4 + 4 + q]; }
            while (true) {
                u32 g0 = h16[s0 * 64 + lane];
                u32 g1 = h16[s1 * 64 + lane];
                int en = e + 2;
                int more = (en + 2 <= e1);
                float d0l = 0.f, d0h = 0.f, d1l = 0.f, d1h = 0.f;
                edot4(A0, wlo, whi, d0l, d0h);
                edot4(A1, wlo, whi, d1l, d1h);
                int ns0 = s0, ns1 = s1;
                if (more) {
                    ns0 = cssrc[en]; ns1 = cssrc[en + 1];
#pragma unroll
                    for (int q = 0; q < 4; q++) { A0[q] = cea[en * 4 + q]; A1[q] = cea[en * 4 + 4 + q]; }
                }
                half2_t hh0 = as_half2(g0), hh1 = as_half2(g1);
                al0 += fmaxf(d0l + blo + (float)hh0.x, 0.f);
                ah0 += fmaxf(d0h + bhi + (float)hh0.y, 0.f);
                al1 += fmaxf(d1l + blo + (float)hh1.x, 0.f);
                ah1 += fmaxf(d1h + bhi + (float)hh1.y, 0.f);
                e = en;
                if (!more) break;
                s0 = ns0; s1 = ns1;
            }
        }
        if (e < e1) {  // tail: one edge
            int s0 = cssrc[e];
            u32x4 A0[4];
#pragma unroll
            for (int q = 0; q < 4; q++) A0[q] = cea[e * 4 + q];
            float dl = 0.f, dh = 0.f;
            edot4(A0, wlo, whi, dl, dh);
            half2_t hh = as_half2(h16[s0 * 64 + lane]);
            al0 += fmaxf(dl + blo + (float)hh.x, 0.f);
            ah0 += fmaxf(dh + bhi + (float)hh.y, 0.f);
        }
        half2_t self = as_half2(h16[n * 64 + lane]);
        z16[n * 64 + lane] = pack_half2((float)self.x + al0 + al1,
                                        (float)self.y + ah0 + ah1);
    }
}

// ---------------- fused MLP via MFMA (fp16 in, fp32 accum) ----------------
// Block: 128 nodes x 128 feats, 4 waves. Wave w owns feature tiles {2w, 2w+1}.
// v_mfma_f32_16x16x32_f16 layouts (m89/m91-verified):
//   A lane l elem j: A[l&15][8*(l>>4)+j]; B lane l elem j: B[8*(l>>4)+j][l&15]
//   D lane l reg r:  D[4*(l>>4)+r][l&15]
// LDS tiles [row][256B] with 16B-slot XOR swizzle (slot ^= row&7) -> bank-balanced.
// h1 kept in LDS between GEMMs; BN stats fused via shfl-reduce + atomics.
__global__ __launch_bounds__(256) void mlp_mfma_kernel(
    const u32* __restrict__ z16,
    const _Float16* __restrict__ w1t, const float* __restrict__ b1_,
    const _Float16* __restrict__ w2t, const float* __restrict__ b2_,
    float* __restrict__ z2, float* __restrict__ stats) {
    __shared__ __align__(16) char lds[65536];
    char* zh = lds;            // 32 KB: z tile (k'-order), later h1 tile
    char* wh = lds + 32768;    // 32 KB: W1T, later W2T
    int t = threadIdx.x, l = t & 63, w = t >> 6;
    int li = l & 15, rg = l >> 4;
    int base = blockIdx.x * 128;

    // stage z tile (global uint4 coalesced -> swizzled b128 LDS write)
#pragma unroll
    for (int rep = 0; rep < 8; rep++) {
        int c = t + rep * 256;
        int n = c >> 4, s = c & 15;
        int gn = base + n;
        uint4 v = make_uint4(0u, 0u, 0u, 0u);
        if (gn < N_NODES) v = *(const uint4*)(z16 + (size_t)gn * 64 + s * 4);
        *(uint4*)(zh + n * 256 + ((s ^ (n & 7)) << 4)) = v;
    }
    // stage W1T
#pragma unroll
    for (int rep = 0; rep < 8; rep++) {
        int c = t + rep * 256;
        int f = c >> 4, s = c & 15;
        uint4 v = *(const uint4*)((const char*)w1t + f * 256 + s * 16);
        *(uint4*)(wh + f * 256 + ((s ^ (f & 7)) << 4)) = v;
    }
    __syncthreads();

    int f0 = w * 32 + li;
    int f1 = w * 32 + 16 + li;

    f32x4 acc0[8], acc1[8];
    {
        float bva = b1_[f0], bvb = b1_[f1];
#pragma unroll
        for (int m = 0; m < 8; m++) {
            acc0[m] = (f32x4){bva, bva, bva, bva};
            acc1[m] = (f32x4){bvb, bvb, bvb, bvb};
        }
    }
    // GEMM1: h1 = relu(z @ W1 + b1)
#pragma unroll
    for (int kt = 0; kt < 4; kt++) {
        int s = kt * 4 + rg;
        half8 bf0 = *(const half8*)(wh + f0 * 256 + ((s ^ (f0 & 7)) << 4));
        half8 bf1 = *(const half8*)(wh + f1 * 256 + ((s ^ (f1 & 7)) << 4));
#pragma unroll
        for (int m = 0; m < 8; m++) {
            int n = m * 16 + li;
            half8 af = *(const half8*)(zh + n * 256 + ((s ^ (n & 7)) << 4));
            acc0[m] = __builtin_amdgcn_mfma_f32_16x16x32_f16(af, bf0, acc0[m], 0, 0, 0);
            acc1[m] = __builtin_amdgcn_mfma_f32_16x16x32_f16(af, bf1, acc1[m], 0, 0, 0);
        }
    }
    __syncthreads();   // all GEMM1 reads of zh/wh complete

    // write h1 (relu, fp16) into zh at [node][feat] (identity k for GEMM2)
#pragma unroll
    for (int m = 0; m < 8; m++) {
#pragma unroll
        for (int r = 0; r < 4; r++) {
            int n = m * 16 + rg * 4 + r;
            int s0 = f0 >> 3;
            *(_Float16*)(zh + n * 256 + ((s0 ^ (n & 7)) << 4) + (f0 & 7) * 2) =
                (_Float16)fmaxf(acc0[m][r], 0.f);
            int s1 = f1 >> 3;
            *(_Float16*)(zh + n * 256 + ((s1 ^ (n & 7)) << 4) + (f1 & 7) * 2) =
                (_Float16)fmaxf(acc1[m][r], 0.f);
        }
    }
    // stage W2T into wh
#pragma unroll
    for (int rep = 0; rep < 8; rep++) {
        int c = t + rep * 256;
        int f = c >> 4, s = c & 15;
        uint4 v = *(const uint4*)((const char*)w2t + f * 256 + s * 16);
        *(uint4*)(wh + f * 256 + ((s ^ (f & 7)) << 4)) = v;
    }
    __syncthreads();

    // GEMM2: z2 = h1 @ W2 + b2
    {
        float cva = b2_[f0], cvb = b2_[f1];
#pragma unroll
        for (int m = 0; m < 8; m++) {
            acc0[m] = (f32x4){cva, cva, cva, cva};
            acc1[m] = (f32x4){cvb, cvb, cvb, cvb};
        }
    }
#pragma unroll
    for (int kt = 0; kt < 4; kt++) {
        int s = kt * 4 + rg;
        half8 bf0 = *(const half8*)(wh + f0 * 256 + ((s ^ (f0 & 7)) << 4));
        half8 bf1 = *(const half8*)(wh + f1 * 256 + ((s ^ (f1 & 7)) << 4));
#pragma unroll
        for (int m = 0; m < 8; m++) {
            int n = m * 16 + li;
            half8 af = *(const half8*)(zh + n * 256 + ((s ^ (n & 7)) << 4));
            acc0[m] = __builtin_amdgcn_mfma_f32_16x16x32_f16(af, bf0, acc0[m], 0, 0, 0);
            acc1[m] = __builtin_amdgcn_mfma_f32_16x16x32_f16(af, bf1, acc1[m], 0, 0, 0);
        }
    }

    // epilogue: store z2 (fp32) + fused BN stats
    float s0 = 0.f, q0 = 0.f, s1 = 0.f, q1 = 0.f;
#pragma unroll
    for (int m = 0; m < 8; m++) {
#pragma unroll
        for (int r = 0; r < 4; r++) {
            int gn = base + m * 16 + rg * 4 + r;
            if (gn < N_NODES) {
                float v0 = acc0[m][r], v1 = acc1[m][r];
                z2[(size_t)gn * 128 + f0] = v0;
                z2[(size_t)gn * 128 + f1] = v1;
                s0 += v0; q0 = fmaf(v0, v0, q0);
                s1 += v1; q1 = fmaf(v1, v1, q1);
            }
        }
    }
    s0 += __shfl_xor(s0, 16); s0 += __shfl_xor(s0, 32);
    q0 += __shfl_xor(q0, 16); q0 += __shfl_xor(q0, 32);
    s1 += __shfl_xor(s1, 16); s1 += __shfl_xor(s1, 32);
    q1 += __shfl_xor(q1, 16); q1 += __shfl_xor(q1, 32);
    if (rg == 0) {
        unsafeAtomicAdd(&stats[f0], s0);
        unsafeAtomicAdd(&stats[128 + f0], q0);
        unsafeAtomicAdd(&stats[f1], s1);
        unsafeAtomicAdd(&stats[128 + f1], q1);
    }
}

// ---------------- batchnorm + relu + residual (paired features) ----------------
__global__ __launch_bounds__(256) void bn_kernel(
    const float* __restrict__ z2, const float* __restrict__ stats,
    const float* __restrict__ gamma, const float* __restrict__ beta,
    u32* __restrict__ h16, float* __restrict__ out, int write_out) {
    int idx = blockIdx.x * 256 + threadIdx.x;
    if (idx >= N_NODES * 64) return;
    int n = idx >> 6, l = idx & 63;
    const float inv_n = 1.0f / (float)N_NODES;
    float mu_l = stats[l] * inv_n;
    float mu_h = stats[64 + l] * inv_n;
    float var_l = stats[HIDDEN + l] * inv_n - mu_l * mu_l;
    float var_h = stats[HIDDEN + 64 + l] * inv_n - mu_h * mu_h;
    float inv_l = rsqrtf(var_l + BN_EPS);
    float inv_h = rsqrtf(var_h + BN_EPS);
    float zl = (z2[n * HIDDEN + l]      - mu_l) * inv_l * gamma[l]      + beta[l];
    float zh = (z2[n * HIDDEN + 64 + l] - mu_h) * inv_h * gamma[64 + l] + beta[64 + l];
    zl = fmaxf(zl, 0.f);
    zh = fmaxf(zh, 0.f);
    half2_t hh = as_half2(h16[idx]);
    float hn_l = fmaf(RES_SCALE, (float)hh.x, zl);
    float hn_h = fmaf(RES_SCALE, (float)hh.y, zh);
    h16[idx] = pack_half2(hn_l, hn_h);
    if (write_out) {
        out[n * HIDDEN + l] = hn_l;
        out[n * HIDDEN + 64 + l] = hn_h;
    }
}

extern "C" void kernel_launch(void* const* d_in, const int* in_sizes, int n_in,
                              void* d_out, int out_size, void* d_ws, size_t ws_size,
                              hipStream_t stream) {
    const float* x     = (const float*)d_in[0];
    const int*   ei    = (const int*)d_in[1];
    const float* ea    = (const float*)d_in[2];
    const float* We    = (const float*)d_in[3];
    const float* be    = (const float*)d_in[4];
    const float* W1    = (const float*)d_in[5];
    const float* b1    = (const float*)d_in[6];
    const float* W2    = (const float*)d_in[7];
    const float* b2    = (const float*)d_in[8];
    const float* gamma = (const float*)d_in[9];
    const float* beta  = (const float*)d_in[10];
    float* out = (float*)d_out;

    char* wsp = (char*)d_ws;
    const size_t NH = (size_t)N_NODES * HIDDEN;
    u32*      h16    = (u32*)wsp;      wsp += (size_t)N_NODES * 64 * 4;        // 12.8 MB
    u32*      z16    = (u32*)wsp;      wsp += (size_t)N_NODES * 64 * 4;        // 12.8 MB
    float*    z2     = (float*)wsp;    wsp += NH * 4;                          // 25.6 MB
    _Float16* ea_perm= (_Float16*)wsp; wsp += (size_t)N_EDGES * EDGE_DIM * 2;  // 51.2 MB
    _Float16* w1t    = (_Float16*)wsp; wsp += (size_t)NUM_LAYERS * 128 * 128 * 2;
    _Float16* w2t    = (_Float16*)wsp; wsp += (size_t)NUM_LAYERS * 128 * 128 * 2;
    float*    statsA = (float*)wsp;    wsp += (size_t)NUM_LAYERS * 256 * 4;
    u32*      deg    = (u32*)wsp;      wsp += (size_t)N_NODES * 4;
    u32*      cursor = (u32*)wsp;      wsp += (size_t)N_NODES * 4;
    int*      ssrc   = (int*)wsp;      wsp += (size_t)N_EDGES * 4;
    u32*      off    = (u32*)wsp;      wsp += (size_t)(N_NODES + 1) * 4;
    u32*      bsum   = (u32*)wsp;      wsp += (size_t)SCAN_NB * 4;
    u32*      bbase  = (u32*)wsp;      wsp += (size_t)SCAN_NB * 4;

    const int p_blocks  = (N_NODES * 64 + 255) / 256;       // 12500
    const int e_blocks  = (N_EDGES + 255) / 256;            // 3125
    const int m_blocks  = (N_NODES + 127) / 128;            // 391
    const int w_blocks  = (NUM_LAYERS * 128 * 128 + 255) / 256; // 192

    // CSR build + weight precompute (once per call)
    init_kernel<<<p_blocks, 256, 0, stream>>>(x, h16, deg, statsA);
    hist_kernel<<<e_blocks, 256, 0, stream>>>(ei, deg);
    scan1_kernel<<<SCAN_NB, 256, 0, stream>>>(deg, bsum);
    scan2_kernel<<<1, 256, 0, stream>>>(bsum, bbase, off);
    scan3_kernel<<<SCAN_NB, 256, 0, stream>>>(deg, bbase, off, cursor);
    scatter_kernel<<<e_blocks, 256, 0, stream>>>(ei, cursor, ssrc, ea, ea_perm);
    wconv_kernel<<<w_blocks, 256, 0, stream>>>(W1, W2, w1t, w2t);

    for (int l = 0; l < NUM_LAYERS; l++) {
        agg_perm_kernel<<<4096, 256, 0, stream>>>(
            h16, ea_perm, ssrc, off,
            We + (size_t)l * EDGE_DIM * HIDDEN, be + (size_t)l * HIDDEN, z16);
        mlp_mfma_kernel<<<m_blocks, 256, 0, stream>>>(
            z16, w1t + (size_t)l * 16384, b1 + (size_t)l * HIDDEN,
            w2t + (size_t)l * 16384, b2 + (size_t)l * HIDDEN,
            z2, statsA + (size_t)l * 256);
        bn_kernel<<<p_blocks, 256, 0, stream>>>(
            z2, statsA + (size_t)l * 256, gamma + (size_t)l * HIDDEN, beta + (size_t)l * HIDDEN,
            h16, out, (l == NUM_LAYERS - 1) ? 1 : 0);
    }
}